// Round 7
// baseline (525.818 us; speedup 1.0000x reference)
//
#include <hip/hip_runtime.h>
#include <hip/hip_cooperative_groups.h>
#include <math.h>

namespace cg = cooperative_groups;

#define Bn   128
#define Rn   1152
#define CIn  8
#define Cn   10
#define On   16
#define BO   2048      // Bn*On
#define CBO  20480     // Cn*BO
#define RB   24        // r's per block
#define PSEG 48        // Rn / RB
#define GRID 480       // Cn * PSEG; co-resident at 2 blocks/CU (512 >= 480)

#define F4SET0(a)      a.x=0.f; a.y=0.f; a.z=0.f; a.w=0.f
#define F4FMA(acc,s,v) acc.x=fmaf(s,v.x,acc.x); acc.y=fmaf(s,v.y,acc.y); \
                       acc.z=fmaf(s,v.z,acc.z); acc.w=fmaf(s,v.w,acc.w)

// One cooperative kernel: transpose -> [pass -> combine] x3 -> final.
// Pass phase: block=(c,seg of 24 r); 4 waves = b-quarters; lane = og(4)x bq(16);
// thread owns 2b x 4o, accumulates in registers, writes one partial per (seg,c,b,o).
__global__ __launch_bounds__(256, 2)
void fused_kernel(const float* __restrict__ X, const float* __restrict__ W,
                  float* __restrict__ XT, float* __restrict__ PT,
                  float* __restrict__ PL, float* __restrict__ S,
                  float* __restrict__ N2, float* __restrict__ out)
{
    cg::grid_group grid = cg::this_grid();

    const int blk  = blockIdx.x;
    const int tid  = threadIdx.x;
    const int c    = blk / PSEG;
    const int seg  = blk - c * PSEG;
    const int r0   = seg * RB;
    const int wv   = tid >> 6;
    const int lane = tid & 63;
    const int bq   = lane & 15;
    const int og   = lane >> 4;

    __shared__ float red[4];

    // ---- phase 0: transpose x[b][r][i] -> XT[r][g][b] (float4 units); zero N2
    {
        const int gtid = blk * 256 + tid;
        for (int i = gtid; i < Rn * 256; i += GRID * 256) {
            const int r = i >> 8;
            const int k = i & 255;
            const int g = k >> 7;
            const int b = k & 127;
            float4 v = *(const float4*)(X + (size_t)b * (Rn * CIn) + r * CIn + g * 4);
            ((float4*)XT)[i] = v;
        }
        if (gtid < 4) N2[gtid] = 0.0f;
    }
    grid.sync();

    const float4* XT4 = (const float4*)XT;
    const float*  wc  = W + (size_t)c * Rn * 128 + (size_t)r0 * 128 + og * 4;

    for (int pass = 1; pass <= 3; ++pass) {
        // ---- Vsum (pre-scaled by log2e) from previous passes' S, N2
        float4 vs[2]; F4SET0(vs[0]); F4SET0(vs[1]);
        if (pass > 1) {
            for (int t = 0; t < pass - 1; ++t) {
                const float n2   = N2[t];
                const float coef = n2 / ((1.0f + n2) * sqrtf(n2)) * 1.4426950408889634f;
                #pragma unroll
                for (int j = 0; j < 2; ++j) {
                    const int b = wv * 32 + j * 16 + bq;
                    const float4 s4 = *(const float4*)(S + t * CBO + c * BO + b * On + og * 4);
                    F4FMA(vs[j], coef, s4);
                }
            }
        }

        float4 tacc[2], lacc[2];
        F4SET0(tacc[0]); F4SET0(tacc[1]); F4SET0(lacc[0]); F4SET0(lacc[1]);

        if (pass == 1) {
            #pragma unroll 2
            for (int rr = 0; rr < RB; ++rr) {
                const float* wr = wc + rr * 128;
                float4 xa[2], xb[2];
                #pragma unroll
                for (int j = 0; j < 2; ++j) {
                    const int b = wv * 32 + j * 16 + bq;
                    xa[j] = XT4[(r0 + rr) * 256 + b];
                    xb[j] = XT4[(r0 + rr) * 256 + 128 + b];
                }
                float4 wf0 = *(const float4*)(wr + 0 * On);
                float4 wf1 = *(const float4*)(wr + 1 * On);
                float4 wf2 = *(const float4*)(wr + 2 * On);
                float4 wf3 = *(const float4*)(wr + 3 * On);
                float4 u[2];
                #pragma unroll
                for (int j = 0; j < 2; ++j) {
                    u[j].x = xa[j].x * wf0.x; u[j].y = xa[j].x * wf0.y;
                    u[j].z = xa[j].x * wf0.z; u[j].w = xa[j].x * wf0.w;
                    F4FMA(u[j], xa[j].y, wf1);
                    F4FMA(u[j], xa[j].z, wf2);
                    F4FMA(u[j], xa[j].w, wf3);
                }
                wf0 = *(const float4*)(wr + 4 * On);
                wf1 = *(const float4*)(wr + 5 * On);
                wf2 = *(const float4*)(wr + 6 * On);
                wf3 = *(const float4*)(wr + 7 * On);
                #pragma unroll
                for (int j = 0; j < 2; ++j) {
                    F4FMA(u[j], xb[j].x, wf0);
                    F4FMA(u[j], xb[j].y, wf1);
                    F4FMA(u[j], xb[j].z, wf2);
                    F4FMA(u[j], xb[j].w, wf3);
                    tacc[j].x += u[j].x; tacc[j].y += u[j].y;
                    tacc[j].z += u[j].z; tacc[j].w += u[j].w;
                }
            }
        } else {
            #pragma unroll 2
            for (int rr = 0; rr < RB; ++rr) {
                const float* wr = wc + rr * 128;
                float4 xa[2], xb[2];
                #pragma unroll
                for (int j = 0; j < 2; ++j) {
                    const int b = wv * 32 + j * 16 + bq;
                    xa[j] = XT4[(r0 + rr) * 256 + b];
                    xb[j] = XT4[(r0 + rr) * 256 + 128 + b];
                }
                float4 wf0 = *(const float4*)(wr + 0 * On);
                float4 wf1 = *(const float4*)(wr + 1 * On);
                float4 wf2 = *(const float4*)(wr + 2 * On);
                float4 wf3 = *(const float4*)(wr + 3 * On);
                float4 u[2];
                #pragma unroll
                for (int j = 0; j < 2; ++j) {
                    u[j].x = xa[j].x * wf0.x; u[j].y = xa[j].x * wf0.y;
                    u[j].z = xa[j].x * wf0.z; u[j].w = xa[j].x * wf0.w;
                    F4FMA(u[j], xa[j].y, wf1);
                    F4FMA(u[j], xa[j].z, wf2);
                    F4FMA(u[j], xa[j].w, wf3);
                }
                wf0 = *(const float4*)(wr + 4 * On);
                wf1 = *(const float4*)(wr + 5 * On);
                wf2 = *(const float4*)(wr + 6 * On);
                wf3 = *(const float4*)(wr + 7 * On);
                #pragma unroll
                for (int j = 0; j < 2; ++j) {
                    F4FMA(u[j], xb[j].x, wf0);
                    F4FMA(u[j], xb[j].y, wf1);
                    F4FMA(u[j], xb[j].z, wf2);
                    F4FMA(u[j], xb[j].w, wf3);
                    float4 e;
                    e.x = exp2f(u[j].x * vs[j].x);
                    e.y = exp2f(u[j].y * vs[j].y);
                    e.z = exp2f(u[j].z * vs[j].z);
                    e.w = exp2f(u[j].w * vs[j].w);
                    lacc[j].x += e.x; lacc[j].y += e.y;
                    lacc[j].z += e.z; lacc[j].w += e.w;
                    tacc[j].x = fmaf(e.x, u[j].x, tacc[j].x);
                    tacc[j].y = fmaf(e.y, u[j].y, tacc[j].y);
                    tacc[j].z = fmaf(e.z, u[j].z, tacc[j].z);
                    tacc[j].w = fmaf(e.w, u[j].w, tacc[j].w);
                }
            }
        }

        // ---- store partials (each (b,o) owned by exactly one thread)
        #pragma unroll
        for (int j = 0; j < 2; ++j) {
            const int b   = wv * 32 + j * 16 + bq;
            const int idx = seg * CBO + c * BO + b * On + og * 4;
            *(float4*)(PT + idx) = tacc[j];
            if (pass > 1) *(float4*)(PL + idx) = lacc[j];
        }
        grid.sync();

        // ---- combine: first 80 blocks; thread i owns one (c,b,o)
        if (blk < 80) {
            const int i = blk * 256 + tid;
            float T = 0.0f, L = 0.0f;
            #pragma unroll 8
            for (int s2 = 0; s2 < PSEG; ++s2) T += PT[s2 * CBO + i];
            if (pass == 1) {
                L = (float)Rn;
            } else {
                #pragma unroll 8
                for (int s2 = 0; s2 < PSEG; ++s2) L += PL[s2 * CBO + i];
            }
            const float sv = T / L;
            S[(pass - 1) * CBO + i] = sv;
            float sq = sv * sv;
            #pragma unroll
            for (int d = 1; d < 64; d <<= 1) sq += __shfl_xor(sq, d);
            if (lane == 0) red[wv] = sq;
            __syncthreads();
            if (tid == 0)
                atomicAdd(N2 + (pass - 1), red[0] + red[1] + red[2] + red[3]);
        }
        grid.sync();
    }

    // ---- final: out = squash-coef(n2_3) * s3
    if (blk < 80) {
        const int i = blk * 256 + tid;
        const float n2   = N2[2];
        const float coef = n2 / ((1.0f + n2) * sqrtf(n2));
        out[i] = coef * S[2 * CBO + i];
    }
}

extern "C" void kernel_launch(void* const* d_in, const int* in_sizes, int n_in,
                              void* d_out, int out_size, void* d_ws, size_t ws_size,
                              hipStream_t stream)
{
    const float* X = (const float*)d_in[0];
    const float* W = (const float*)d_in[1];
    float* ws  = (float*)d_ws;
    float* XT  = ws;                          // Rn*Bn*CIn = 1,179,648 floats
    float* N2  = XT + Rn * Bn * CIn;          // 4 floats
    float* PT  = N2 + 4;                      // PSEG*CBO = 983,040 floats
    float* PL  = PT + PSEG * CBO;             // PSEG*CBO
    float* S   = PL + PSEG * CBO;             // 3*CBO
    float* out = (float*)d_out;

    void* args[] = { (void*)&X, (void*)&W, (void*)&XT, (void*)&PT,
                     (void*)&PL, (void*)&S, (void*)&N2, (void*)&out };
    hipLaunchCooperativeKernel((const void*)fused_kernel,
                               dim3(GRID), dim3(256), args, 0, stream);
}

// Round 8
// 136.591 us; speedup vs baseline: 3.8496x; 3.8496x over previous
//
#include <hip/hip_runtime.h>
#include <math.h>

#define Bn   128
#define Rn   1152
#define CIn  8
#define Cn   10
#define On   16
#define BO   2048      // Bn*On
#define CBO  20480     // Cn*BO
#define RB   24        // r's per block
#define PSEG 48        // Rn / RB
#define NB2  80        // combine blocks (80*256 = 20480)

#define F4SET0(a)      a.x=0.f; a.y=0.f; a.z=0.f; a.w=0.f
#define F4FMA(acc,s,v) acc.x=fmaf(s,v.x,acc.x); acc.y=fmaf(s,v.y,acc.y); \
                       acc.z=fmaf(s,v.z,acc.z); acc.w=fmaf(s,v.w,acc.w)

// ---- transpose x[b][r][i] -> XT[r][g][b][q]  (i = g*4+q), float4 units
__global__ __launch_bounds__(256)
void transpose_x(const float* __restrict__ X, float* __restrict__ XT)
{
    const int r = blockIdx.x;
    const int b = threadIdx.x & 127;
    const int g = threadIdx.x >> 7;
    float4 v = *(const float4*)(X + (size_t)b * (Rn * CIn) + r * CIn + g * 4);
    ((float4*)XT)[r * 256 + g * 128 + b] = v;
}

// ---- pass kernel: wave = (bh, o-quad). lane = local b (64 lanes).
// W per r per wave = 32 floats, wave-uniform -> scalar (s_load) pipe.
// X per r per wave = 2 coalesced 1KB float4 loads (address = f(lane) only).
// No LDS, no barriers, no atomics. Grid: 960 = Cn(10) * 2 bh * PSEG(48).
template<int PASS>
__global__ __launch_bounds__(256)
void pass_kernel(const float* __restrict__ XT, const float* __restrict__ W,
                 const float* __restrict__ S, const float* __restrict__ N2P,
                 float* __restrict__ PT, float* __restrict__ PL)
{
    const int blk  = blockIdx.x;
    const int c    = blk / 96;
    const int rem  = blk - c * 96;
    const int bh   = rem / PSEG;
    const int seg  = rem - bh * PSEG;
    const int tid  = threadIdx.x;
    const int og   = __builtin_amdgcn_readfirstlane(tid >> 6);  // wave-uniform o-quad
    const int lane = tid & 63;
    const int b    = bh * 64 + lane;
    const int r0   = seg * RB;

    // Vsum (pre-scaled by log2e) from previous passes' S; n2 via N2P partial sums
    float4 vs; F4SET0(vs);
    if (PASS > 1) {
        #pragma unroll
        for (int t = 0; t < PASS - 1; ++t) {
            float n2 = 0.0f;
            #pragma unroll 8
            for (int j = 0; j < NB2; ++j) n2 += N2P[t * NB2 + j];
            const float coef = n2 / ((1.0f + n2) * sqrtf(n2)) * 1.4426950408889634f;
            const float4 s4 = *(const float4*)(S + t * CBO + c * BO + b * On + og * 4);
            F4FMA(vs, coef, s4);
        }
    }

    float4 tacc, lacc;
    F4SET0(tacc); F4SET0(lacc);

    const float4* XT4 = (const float4*)XT;
    const float*  wb  = W + ((size_t)c * Rn + r0) * 128 + og * 4;

    #pragma unroll 2
    for (int rr = 0; rr < RB; ++rr) {
        const int r = r0 + rr;
        // x fragment: 8 i-values for this lane's b (two coalesced float4 loads)
        const float4 xa = XT4[r * 256 + b];          // i = 0..3
        const float4 xb = XT4[r * 256 + 128 + b];    // i = 4..7
        // W fragment: w_i = W[c][r][i][og*4 .. +3], wave-uniform -> s_load
        const float* wr = wb + rr * 128;
        const float4 w0 = *(const float4*)(wr + 0 * On);
        const float4 w1 = *(const float4*)(wr + 1 * On);
        const float4 w2 = *(const float4*)(wr + 2 * On);
        const float4 w3 = *(const float4*)(wr + 3 * On);
        const float4 w4 = *(const float4*)(wr + 4 * On);
        const float4 w5 = *(const float4*)(wr + 5 * On);
        const float4 w6 = *(const float4*)(wr + 6 * On);
        const float4 w7 = *(const float4*)(wr + 7 * On);
        // u over this thread's 4 o's
        float4 u;
        u.x = xa.x * w0.x; u.y = xa.x * w0.y; u.z = xa.x * w0.z; u.w = xa.x * w0.w;
        F4FMA(u, xa.y, w1);
        F4FMA(u, xa.z, w2);
        F4FMA(u, xa.w, w3);
        F4FMA(u, xb.x, w4);
        F4FMA(u, xb.y, w5);
        F4FMA(u, xb.z, w6);
        F4FMA(u, xb.w, w7);
        if (PASS == 1) {
            tacc.x += u.x; tacc.y += u.y; tacc.z += u.z; tacc.w += u.w;
        } else {
            float4 e;
            e.x = exp2f(u.x * vs.x);
            e.y = exp2f(u.y * vs.y);
            e.z = exp2f(u.z * vs.z);
            e.w = exp2f(u.w * vs.w);
            lacc.x += e.x; lacc.y += e.y; lacc.z += e.z; lacc.w += e.w;
            tacc.x = fmaf(e.x, u.x, tacc.x);
            tacc.y = fmaf(e.y, u.y, tacc.y);
            tacc.z = fmaf(e.z, u.z, tacc.z);
            tacc.w = fmaf(e.w, u.w, tacc.w);
        }
    }

    // each (b, o-quad) owned by exactly one thread -> plain store
    const int idx = seg * CBO + c * BO + b * On + og * 4;
    *(float4*)(PT + idx) = tacc;
    if (PASS > 1) *(float4*)(PL + idx) = lacc;
}

// sum partials over PSEG segs; s = T/L; store S slot; per-block sum(s^2) -> N2P
template<int PASS>
__global__ __launch_bounds__(256)
void combine_kernel(const float* __restrict__ PT, const float* __restrict__ PL,
                    float* __restrict__ Sout, float* __restrict__ n2p_out)
{
    const int i = blockIdx.x * 256 + threadIdx.x;   // 80 blocks * 256 = 20480
    float T = 0.0f, L = 0.0f;
    #pragma unroll 8
    for (int s = 0; s < PSEG; ++s) T += PT[s * CBO + i];
    if (PASS == 1) {
        L = (float)Rn;   // exp(0)=1 summed over all r
    } else {
        #pragma unroll 8
        for (int s = 0; s < PSEG; ++s) L += PL[s * CBO + i];
    }
    const float sv = T / L;
    Sout[i] = sv;
    float sq = sv * sv;
    #pragma unroll
    for (int d = 1; d < 64; d <<= 1) sq += __shfl_xor(sq, d);
    __shared__ float red[4];
    if ((threadIdx.x & 63) == 0) red[threadIdx.x >> 6] = sq;
    __syncthreads();
    if (threadIdx.x == 0)
        n2p_out[blockIdx.x] = red[0] + red[1] + red[2] + red[3];  // no atomics
}

__global__ __launch_bounds__(256)
void final_kernel(const float* __restrict__ S2, const float* __restrict__ n2p,
                  float* __restrict__ out)
{
    float n2 = 0.0f;
    #pragma unroll 8
    for (int j = 0; j < NB2; ++j) n2 += n2p[j];     // uniform, L2-hot
    const float coef = n2 / ((1.0f + n2) * sqrtf(n2));
    const int i = blockIdx.x * 256 + threadIdx.x;
    out[i] = coef * S2[i];
}

extern "C" void kernel_launch(void* const* d_in, const int* in_sizes, int n_in,
                              void* d_out, int out_size, void* d_ws, size_t ws_size,
                              hipStream_t stream)
{
    const float* X = (const float*)d_in[0];
    const float* W = (const float*)d_in[1];
    float* ws  = (float*)d_ws;
    float* XT  = ws;                          // Rn*Bn*CIn = 1,179,648 floats
    float* PT  = XT + Rn * Bn * CIn;          // PSEG*CBO = 983,040
    float* PL  = PT + PSEG * CBO;             // PSEG*CBO
    float* S   = PL + PSEG * CBO;             // 3*CBO
    float* N2P = S + 3 * CBO;                 // 3*NB2

    transpose_x<<<Rn, 256, 0, stream>>>(X, XT);
    pass_kernel<1><<<960, 256, 0, stream>>>(XT, W, S, N2P, PT, PL);
    combine_kernel<1><<<NB2, 256, 0, stream>>>(PT, PL, S + 0 * CBO, N2P + 0 * NB2);
    pass_kernel<2><<<960, 256, 0, stream>>>(XT, W, S, N2P, PT, PL);
    combine_kernel<2><<<NB2, 256, 0, stream>>>(PT, PL, S + 1 * CBO, N2P + 1 * NB2);
    pass_kernel<3><<<960, 256, 0, stream>>>(XT, W, S, N2P, PT, PL);
    combine_kernel<3><<<NB2, 256, 0, stream>>>(PT, PL, S + 2 * CBO, N2P + 2 * NB2);
    final_kernel<<<NB2, 256, 0, stream>>>(S + 2 * CBO, N2P + 2 * NB2, (float*)d_out);
}